// Round 1
// 239.165 us; speedup vs baseline: 2.1417x; 2.1417x over previous
//
#include <hip/hip_runtime.h>
#include <stdint.h>

typedef unsigned short u16;
typedef __bf16 bf16x8 __attribute__((ext_vector_type(8)));
typedef float f32x4 __attribute__((ext_vector_type(4)));
typedef float f32x16 __attribute__((ext_vector_type(16)));

#define B_ 4
#define T_ 2048
#define C_ 1024
#define NH_ 16
#define HD_ 64
#define M_ (B_ * T_)   // 8192
#define N1_ (3 * C_)   // 3072
#define NQK_ 2048      // q,k packed stride

__device__ inline u16 f2bf(float f) {
    uint32_t u = __float_as_uint(f);
    u += 0x7FFFu + ((u >> 16) & 1u);
    return (u16)(u >> 16);
}

__device__ inline bf16x8 ld_bf16x8(const u16* p) {
    return *(const bf16x8*)(const void*)p;
}

__device__ inline uint32_t cvtpk_bf16(float a, float b) {
    uint32_t r;
    asm("v_cvt_pk_bf16_f32 %0, %1, %2" : "=v"(r) : "v"(a), "v"(b));
    return r;
}

// ---------------- fp32 -> bf16 elementwise ----------------
__global__ void f32_to_bf16_k(const float* __restrict__ in, u16* __restrict__ out, int n) {
    int i = (blockIdx.x * blockDim.x + threadIdx.x) * 4;
    int stride = gridDim.x * blockDim.x * 4;
    for (; i < n; i += stride) {
        float4 v = *(const float4*)(in + i);
        uint2 o;
        o.x = (uint32_t)f2bf(v.x) | ((uint32_t)f2bf(v.y) << 16);
        o.y = (uint32_t)f2bf(v.z) | ((uint32_t)f2bf(v.w) << 16);
        *(uint2*)(out + i) = o;
    }
}

// ---------------- fp32 [R][Cc] -> bf16 transpose [Cc][R], optional 0.125 scale on out-rows < scaleRows
__global__ void transpose_f32_bf16_k(const float* __restrict__ in, u16* __restrict__ out,
                                     int R, int Cc, int scaleRows) {
    __shared__ float tile[32][33];
    int c0 = blockIdx.x * 32, r0 = blockIdx.y * 32;
    int tx = threadIdx.x, ty = threadIdx.y;  // block (32,8)
#pragma unroll
    for (int i = 0; i < 4; ++i)
        tile[ty + i * 8][tx] = in[(size_t)(r0 + ty + i * 8) * Cc + c0 + tx];
    __syncthreads();
#pragma unroll
    for (int i = 0; i < 4; ++i) {
        int orow = c0 + ty + i * 8;
        float v = tile[tx][ty + i * 8];
        if (orow < scaleRows) v *= 0.125f;   // fold attention scale into Q weights (exact, pow2)
        out[(size_t)orow * R + r0 + tx] = f2bf(v);
    }
}

// ---------------- GEMM: C[M][N] = A[M][K] * Bt[N][K]^T ----------------
// MODE 0: f32 out, leading dim N.  MODE 2: QKV split — cols<2048 -> bf16 @ stride 2048 (Cp),
//         cols>=2048 (V) -> transposed bf16 into Vp as [b][h][d][t].
template <int MODE>
__global__ __launch_bounds__(256) void gemm_bt_k(const u16* __restrict__ A,
                                                 const u16* __restrict__ Bt,
                                                 void* __restrict__ Cp,
                                                 u16* __restrict__ Vp,
                                                 int M, int N, int K) {
    __shared__ u16 As[128 * 32];
    __shared__ u16 Bs[128 * 32];
    const int t = threadIdx.x;
    const int w = t >> 6, l = t & 63;
    const int wr = w >> 1, wc = w & 1;
    const int lr = l & 15, lg = l >> 4;
    const int R0 = blockIdx.x * 128, C0 = blockIdx.y * 128;

    const int sr = t >> 2;
    const int sc = (t & 3) * 8;
    const u16* Ag  = A  + (size_t)(R0 + sr) * K + sc;
    const u16* Ag2 = Ag + (size_t)64 * K;
    const u16* Bg  = Bt + (size_t)(C0 + sr) * K + sc;
    const u16* Bg2 = Bg + (size_t)64 * K;

    f32x4 acc[4][4] = {};
    const int nk = K / 32;

    uint4 a0 = *(const uint4*)Ag;
    uint4 a1 = *(const uint4*)Ag2;
    uint4 b0 = *(const uint4*)Bg;
    uint4 b1 = *(const uint4*)Bg2;

    for (int kt = 0; kt < nk; ++kt) {
        __syncthreads();
        *(uint4*)(As + t * 8)        = a0;
        *(uint4*)(As + t * 8 + 2048) = a1;
        *(uint4*)(Bs + t * 8)        = b0;
        *(uint4*)(Bs + t * 8 + 2048) = b1;
        __syncthreads();
        int kn = (kt + 1 < nk) ? kt + 1 : kt;
        a0 = *(const uint4*)(Ag  + kn * 32);
        a1 = *(const uint4*)(Ag2 + kn * 32);
        b0 = *(const uint4*)(Bg  + kn * 32);
        b1 = *(const uint4*)(Bg2 + kn * 32);

        bf16x8 af[4], bfr[4];
#pragma unroll
        for (int mi = 0; mi < 4; ++mi)
            af[mi] = ld_bf16x8(As + (wr * 64 + mi * 16 + lr) * 32 + lg * 8);
#pragma unroll
        for (int nj = 0; nj < 4; ++nj)
            bfr[nj] = ld_bf16x8(Bs + (wc * 64 + nj * 16 + lr) * 32 + lg * 8);
#pragma unroll
        for (int mi = 0; mi < 4; ++mi)
#pragma unroll
            for (int nj = 0; nj < 4; ++nj)
                acc[mi][nj] = __builtin_amdgcn_mfma_f32_16x16x32_bf16(af[mi], bfr[nj],
                                                                      acc[mi][nj], 0, 0, 0);
    }

    if (MODE == 2 && C0 >= 2048) {
        // V part: write transposed [b][h][d][t], 4 consecutive tokens packed per store
#pragma unroll
        for (int mi = 0; mi < 4; ++mi) {
            int row = R0 + wr * 64 + mi * 16 + lg * 4;
            int bb = row >> 11, tt = row & 2047;
#pragma unroll
            for (int nj = 0; nj < 4; ++nj) {
                int cv = C0 - 2048 + wc * 64 + nj * 16 + lr;
                int hh = cv >> 6, dd = cv & 63;
                ushort4 pk;
                pk.x = f2bf(acc[mi][nj][0]);
                pk.y = f2bf(acc[mi][nj][1]);
                pk.z = f2bf(acc[mi][nj][2]);
                pk.w = f2bf(acc[mi][nj][3]);
                *(ushort4*)(Vp + (((size_t)bb * NH_ + hh) * HD_ + dd) * (size_t)T_ + tt) = pk;
            }
        }
    } else {
#pragma unroll
        for (int mi = 0; mi < 4; ++mi) {
            int row = R0 + wr * 64 + mi * 16 + lg * 4;
#pragma unroll
            for (int nj = 0; nj < 4; ++nj) {
                int col = C0 + wc * 64 + nj * 16 + lr;
#pragma unroll
                for (int r = 0; r < 4; ++r) {
                    if (MODE == 0)
                        ((float*)Cp)[(size_t)(row + r) * N + col] = acc[mi][nj][r];
                    else
                        ((u16*)Cp)[(size_t)(row + r) * NQK_ + col] = f2bf(acc[mi][nj][r]);
                }
            }
        }
    }
}

// ---------------- fused causal flash attention (swapped-operand 32x32 MFMA) ----------------
// grid (T/128, B*NH), 256 thr = 4 waves; wave w owns q rows qBase+w*32..+31.
// KV tiles of 64, double-buffered LDS, 1 barrier/tile. Lane owns q-col = lane&31 of S^T/O^T.
__global__ __launch_bounds__(256, 3) void attn_fwd_k(const u16* __restrict__ qk,   // [B*T][2048]
                                                     const u16* __restrict__ vT,   // [B*H*64][2048]
                                                     u16* __restrict__ attO) {
    __shared__ u16 Ks[2][64 * 64];   // [kv][d], source-preswizzled: byte(row,d)=row*128+(d*2^((row&7)<<4))
    __shared__ u16 Vs[2][64 * 64];   // [d][kv], same swizzle on kv

    const int t = threadIdx.x;
    const int w = t >> 6, l = t & 63;
    const int r0 = l & 31;
    const int hi = l >> 5;
    const int swz = (l & 7) << 4;
    const int qb = gridDim.x - 1 - blockIdx.x;   // heavy tiles first
    const int qBase = qb * 128;
    const int qW = qBase + w * 32;
    const int bh = blockIdx.y;
    const int b = bh >> 4, h = bh & 15;
    const u16* qkB = qk + (size_t)b * T_ * NQK_;

    // Q fragments (B-frag: col=q=lane&31, k=d=dc*16+hi*8+j); 0.125 scale already folded in.
    bf16x8 qf[4];
    {
        const u16* qp = qkB + (size_t)(qW + r0) * NQK_ + h * HD_ + hi * 8;
#pragma unroll
        for (int dc = 0; dc < 4; ++dc) qf[dc] = ld_bf16x8(qp + dc * 16);
    }

    f32x16 accO0 = {}, accO1 = {};   // O^T d-blocks [0..31],[32..63]; lane col = q
    float m = -1e30f, lsum = 0.f;

    const int nt = 2 * qb + 2;
    // staging: thread t covers rows sr, sr+32; 16B chunk (t&7), source pre-swizzled
    const int sr = t >> 3;
    const int sof = ((t & 7) * 8) ^ ((sr & 7) << 3);
    const u16* gK = qkB + (size_t)sr * NQK_ + C_ + h * HD_ + sof;          // + kvBase*NQK_
    const u16* gV = vT + ((size_t)bh * HD_ + sr) * (size_t)T_ + sof;       // + kvBase

    // prologue: stage tile 0
    {
        uint4 k0 = *(const uint4*)(gK);
        uint4 k1 = *(const uint4*)(gK + (size_t)32 * NQK_);
        uint4 v0 = *(const uint4*)(gV);
        uint4 v1 = *(const uint4*)(gV + (size_t)32 * T_);
        *(uint4*)&Ks[0][t * 8] = k0;
        *(uint4*)&Ks[0][t * 8 + 2048] = k1;
        *(uint4*)&Vs[0][t * 8] = v0;
        *(uint4*)&Vs[0][t * 8 + 2048] = v1;
    }
    __syncthreads();

    int cur = 0;
    for (int kt = 0; kt < nt; ++kt) {
        const int kvBase = kt * 64;
        const int knB = (kt + 1 < nt) ? kvBase + 64 : kvBase;  // clamped prefetch
        uint4 nk0 = *(const uint4*)(gK + (size_t)knB * NQK_);
        uint4 nk1 = *(const uint4*)(gK + (size_t)(knB + 32) * NQK_);
        uint4 nv0 = *(const uint4*)(gV + knB);
        uint4 nv1 = *(const uint4*)(gV + (size_t)32 * T_ + knB);

        if (kvBase <= qW) {   // wave-uniform: this wave has unmasked work
            const u16* Kb = Ks[cur];
            const u16* Vb = Vs[cur];

            // S^T = K * Q^T : A-frag rows = kv, B-frag cols = q
            f32x16 s0 = {}, s1 = {};
            __builtin_amdgcn_s_setprio(1);
#pragma unroll
            for (int dc = 0; dc < 4; ++dc) {
                int off = (dc * 32 + hi * 16) ^ swz;
                bf16x8 k0 = ld_bf16x8((const u16*)((const char*)Kb + r0 * 128 + off));
                bf16x8 k1 = ld_bf16x8((const u16*)((const char*)Kb + r0 * 128 + 4096 + off));
                s0 = __builtin_amdgcn_mfma_f32_32x32x16_bf16(k0, qf[dc], s0, 0, 0, 0);
                s1 = __builtin_amdgcn_mfma_f32_32x32x16_bf16(k1, qf[dc], s1, 0, 0, 0);
            }
            __builtin_amdgcn_s_setprio(0);

            // causal mask (only diagonal tiles): lane q = qW+r0, kv_local = (rg&3)+8*(rg>>2)+4*hi
            if (kvBase + 63 > qW) {
                int qrel = qW + r0 - kvBase;
#pragma unroll
                for (int rg = 0; rg < 16; ++rg) {
                    int kv0 = (rg & 3) + 8 * (rg >> 2) + hi * 4;
                    s0[rg] = (kv0 > qrel) ? -1e30f : s0[rg];
                    s1[rg] = (kv0 + 32 > qrel) ? -1e30f : s1[rg];
                }
            }

            // online softmax: in-lane tree + single xor-32 reduce (lane l,l^32 share q)
            float a[8];
#pragma unroll
            for (int i = 0; i < 8; ++i)
                a[i] = fmaxf(fmaxf(s0[i], s0[i + 8]), fmaxf(s1[i], s1[i + 8]));
#pragma unroll
            for (int i = 0; i < 4; ++i) a[i] = fmaxf(a[i], a[i + 4]);
            float mx = fmaxf(fmaxf(a[0], a[1]), fmaxf(a[2], a[3]));
            mx = fmaxf(mx, __shfl_xor(mx, 32));
            float mn = fmaxf(m, mx);
            float corr = __expf(m - mn);
            m = mn;
#pragma unroll
            for (int rg = 0; rg < 16; ++rg) s0[rg] = __expf(s0[rg] - mn);
#pragma unroll
            for (int rg = 0; rg < 16; ++rg) s1[rg] = __expf(s1[rg] - mn);

            float sb[8];
#pragma unroll
            for (int i = 0; i < 8; ++i) sb[i] = (s0[i] + s0[i + 8]) + (s1[i] + s1[i + 8]);
#pragma unroll
            for (int i = 0; i < 4; ++i) sb[i] += sb[i + 4];
            float rs = (sb[0] + sb[1]) + (sb[2] + sb[3]);
            rs += __shfl_xor(rs, 32);
            lsum = lsum * corr + rs;
#pragma unroll
            for (int rg = 0; rg < 16; ++rg) { accO0[rg] *= corr; accO1[rg] *= corr; }

            // P^T B-fragments in-register: cvt_pk pairs + lane^32 exchange
            bf16x8 pb[4];
            {
                uint32_t c0 = cvtpk_bf16(s0[0], s0[1]),   c1 = cvtpk_bf16(s0[2], s0[3]);
                uint32_t c2 = cvtpk_bf16(s0[4], s0[5]),   c3 = cvtpk_bf16(s0[6], s0[7]);
                uint32_t c4 = cvtpk_bf16(s0[8], s0[9]),   c5 = cvtpk_bf16(s0[10], s0[11]);
                uint32_t c6 = cvtpk_bf16(s0[12], s0[13]), c7 = cvtpk_bf16(s0[14], s0[15]);
                uint32_t x0 = (uint32_t)__shfl_xor((int)c0, 32), x1 = (uint32_t)__shfl_xor((int)c1, 32);
                uint32_t x2 = (uint32_t)__shfl_xor((int)c2, 32), x3 = (uint32_t)__shfl_xor((int)c3, 32);
                uint32_t x4 = (uint32_t)__shfl_xor((int)c4, 32), x5 = (uint32_t)__shfl_xor((int)c5, 32);
                uint32_t x6 = (uint32_t)__shfl_xor((int)c6, 32), x7 = (uint32_t)__shfl_xor((int)c7, 32);
                union { uint32_t u[4]; bf16x8 v; } f0, f1;
                f0.u[0] = hi ? x2 : c0;  f0.u[1] = hi ? x3 : c1;
                f0.u[2] = hi ? c2 : x0;  f0.u[3] = hi ? c3 : x1;
                f1.u[0] = hi ? x6 : c4;  f1.u[1] = hi ? x7 : c5;
                f1.u[2] = hi ? c6 : x4;  f1.u[3] = hi ? c7 : x5;
                pb[0] = f0.v; pb[1] = f1.v;
            }
            {
                uint32_t c0 = cvtpk_bf16(s1[0], s1[1]),   c1 = cvtpk_bf16(s1[2], s1[3]);
                uint32_t c2 = cvtpk_bf16(s1[4], s1[5]),   c3 = cvtpk_bf16(s1[6], s1[7]);
                uint32_t c4 = cvtpk_bf16(s1[8], s1[9]),   c5 = cvtpk_bf16(s1[10], s1[11]);
                uint32_t c6 = cvtpk_bf16(s1[12], s1[13]), c7 = cvtpk_bf16(s1[14], s1[15]);
                uint32_t x0 = (uint32_t)__shfl_xor((int)c0, 32), x1 = (uint32_t)__shfl_xor((int)c1, 32);
                uint32_t x2 = (uint32_t)__shfl_xor((int)c2, 32), x3 = (uint32_t)__shfl_xor((int)c3, 32);
                uint32_t x4 = (uint32_t)__shfl_xor((int)c4, 32), x5 = (uint32_t)__shfl_xor((int)c5, 32);
                uint32_t x6 = (uint32_t)__shfl_xor((int)c6, 32), x7 = (uint32_t)__shfl_xor((int)c7, 32);
                union { uint32_t u[4]; bf16x8 v; } f0, f1;
                f0.u[0] = hi ? x2 : c0;  f0.u[1] = hi ? x3 : c1;
                f0.u[2] = hi ? c2 : x0;  f0.u[3] = hi ? c3 : x1;
                f1.u[0] = hi ? x6 : c4;  f1.u[1] = hi ? x7 : c5;
                f1.u[2] = hi ? c6 : x4;  f1.u[3] = hi ? c7 : x5;
                pb[2] = f0.v; pb[3] = f1.v;
            }

            // O^T += V^T * P^T : A-frag rows = d, B-frag cols = q
            __builtin_amdgcn_s_setprio(1);
#pragma unroll
            for (int kvc = 0; kvc < 4; ++kvc) {
                int off = (kvc * 32 + hi * 16) ^ swz;
                bf16x8 v0 = ld_bf16x8((const u16*)((const char*)Vb + r0 * 128 + off));
                bf16x8 v1 = ld_bf16x8((const u16*)((const char*)Vb + r0 * 128 + 4096 + off));
                accO0 = __builtin_amdgcn_mfma_f32_32x32x16_bf16(v0, pb[kvc], accO0, 0, 0, 0);
                accO1 = __builtin_amdgcn_mfma_f32_32x32x16_bf16(v1, pb[kvc], accO1, 0, 0, 0);
            }
            __builtin_amdgcn_s_setprio(0);
        }

        // write next tile into the other buffer (loads had full compute to land)
        {
            u16* dK = &Ks[cur ^ 1][t * 8];
            u16* dV = &Vs[cur ^ 1][t * 8];
            *(uint4*)dK = nk0;
            *(uint4*)(dK + 2048) = nk1;
            *(uint4*)dV = nv0;
            *(uint4*)(dV + 2048) = nv1;
        }
        __syncthreads();
        cur ^= 1;
    }

    // epilogue: lane holds O[q=qW+r0][d = db*32 + 8g + 4*hi + r]
    float inv = 1.0f / lsum;
    u16* op = attO + ((size_t)b * T_ + qW + r0) * C_ + h * HD_;
#pragma unroll
    for (int g = 0; g < 4; ++g) {
        int d0 = g * 8 + hi * 4;
        ushort4 p0, p1;
        p0.x = f2bf(accO0[4 * g + 0] * inv);
        p0.y = f2bf(accO0[4 * g + 1] * inv);
        p0.z = f2bf(accO0[4 * g + 2] * inv);
        p0.w = f2bf(accO0[4 * g + 3] * inv);
        *(ushort4*)(op + d0) = p0;
        p1.x = f2bf(accO1[4 * g + 0] * inv);
        p1.y = f2bf(accO1[4 * g + 1] * inv);
        p1.z = f2bf(accO1[4 * g + 2] * inv);
        p1.w = f2bf(accO1[4 * g + 3] * inv);
        *(ushort4*)(op + 32 + d0) = p1;
    }
}

extern "C" void kernel_launch(void* const* d_in, const int* in_sizes, int n_in,
                              void* d_out, int out_size, void* d_ws, size_t ws_size,
                              hipStream_t stream) {
    const float* x      = (const float*)d_in[0];
    const float* w_attn = (const float*)d_in[1];
    const float* w_proj = (const float*)d_in[2];
    float* out = (float*)d_out;

    char* ws = (char*)d_ws;
    const size_t SZ_XB = (size_t)M_ * C_ * 2;       // 16.78 MB
    const size_t SZ_WA = (size_t)C_ * N1_ * 2;      //  6.29 MB
    const size_t SZ_WP = (size_t)C_ * C_ * 2;       //  2.10 MB
    const size_t SZ_QK = (size_t)M_ * NQK_ * 2;     // 33.55 MB
    const size_t SZ_VT = (size_t)M_ * C_ * 2;       // 16.78 MB
    u16* xb   = (u16*)ws;
    u16* waT  = (u16*)(ws + SZ_XB);
    u16* wpT  = (u16*)(ws + SZ_XB + SZ_WA);
    u16* qkb  = (u16*)(ws + SZ_XB + SZ_WA + SZ_WP);
    u16* vtb  = (u16*)(ws + SZ_XB + SZ_WA + SZ_WP + SZ_QK);
    u16* attO = (u16*)(ws + SZ_XB + SZ_WA + SZ_WP + SZ_QK + SZ_VT);

    f32_to_bf16_k<<<2048, 256, 0, stream>>>(x, xb, M_ * C_);
    dim3 tb(32, 8);
    transpose_f32_bf16_k<<<dim3(N1_ / 32, C_ / 32), tb, 0, stream>>>(w_attn, waT, C_, N1_, C_);
    transpose_f32_bf16_k<<<dim3(C_ / 32, C_ / 32), tb, 0, stream>>>(w_proj, wpT, C_, C_, 0);

    gemm_bt_k<2><<<dim3(M_ / 128, N1_ / 128), 256, 0, stream>>>(xb, waT, qkb, vtb, M_, N1_, C_);
    attn_fwd_k<<<dim3(T_ / 128, B_ * NH_), 256, 0, stream>>>(qkb, vtb, attO);
    gemm_bt_k<0><<<dim3(M_ / 128, C_ / 128), 256, 0, stream>>>(attO, wpT, out, nullptr, M_, C_, C_);
}